// Round 20
// baseline (119.635 us; speedup 1.0000x reference)
//
#include <hip/hip_runtime.h>

// Kalman filter, STATE=16, MEAS=8, T=500000. H==eye(8,16), exploited throughout.
//
// Round-20: serial Riccati replaced by STRUCTURE-PRESERVING DOUBLING (SDA).
// m Riccati steps = f(X) = H + A X (I+GX)^-1 A^T, G,H PSD. Composition:
//   U = (I + H1 G2)^-1 ; A12 = A2 U A1 ; G12 = G1 + A1^T G2 U A1 ;
//   H12 = H2 + A2 U H1 A2^T   (keeps G,H PSD -> every inverse is
//   I + PSD*PSD with eigenvalues >= 1: safe no-pivot GJ, unlike r19's
//   raw symplectic powers which hit a near-zero pivot and exploded).
// kf_prep (1 wave): R^-1 (8-GJ), base map (F, H^T R^-1 H, Q), 5 doublings ->
//   maps for 2^k steps (k=0..5) in ws; Pb0 = F F^T + Q.
// kf_kt (T0+244 blocks): block m<T0 composes maps by binary expansion of m
//   (<=4 compositions), evaluates Pb_m = map(Pb0), solves S K^T = Pb[:8,:]
//   (proven 8-GJ) -> K_t history; block T0-1 emits A=(I-KH)F, Ktilde, A^32
//   (rotated, r18 epilogue). Blocks >= T0 stream z into L2/L3 (r18 prefetch).
// kf_scan (245 x 640): r18 pair scan verbatim (8 ghost + 32 pairs, L=32,
//   defer-xin, DPP-fused steps); head group runs exact t<T0 recursion.

#define TT 500000
#define T0 40
#define L1 32
#define NCHUNK 15624           // ceil((TT-T0)/L1); last chunk = 24 steps
#define GH 8                   // ghost chunks = window entries
#define OWN 64                 // owned chunks per block (32 pairs)
#define NBLK2 245              // ceil(NCHUNK/OWN)
#define NTHR (16 * (GH + OWN/2))   // 640
#define NPF 244                // z-prefetch blocks appended to kf_kt

#define OFF_A    0             // 16x16 rotated  A=(I-KH)F
#define OFF_KR   256           // 16x16 rotated  Ktilde
#define OFF_AL   512           // 16x16 rotated  A^32
#define OFF_KH   784           // T0*128 plain K_t history (ends 5904)
#define OFF_PB0  5904          // 16x16 Pb0 = F F^T + Q
#define OFF_MAP  6160          // 6 maps x 768 (A,G,H each 256)

// single-wave LDS fence: order ds_write -> ds_read without draining vmcnt
#define FENCE_LDS() do { \
  asm volatile("s_waitcnt lgkmcnt(0)" ::: "memory"); \
  __builtin_amdgcn_sched_barrier(0); \
} while (0)

// DPP-fused FMA: d += rot_S(x) * a; dep keeps the DPP source >=2 VALU old.
#define FMACDPP(d, x, a, S) \
  asm("v_fmac_f32_dpp %0, %1, %2 row_ror:" #S " row_mask:0xf bank_mask:0xf" \
      : "+v"(d) : "v"(x), "v"(a))
#define MULDPPD(d, x, a, dep, S) \
  asm("v_mul_f32_dpp %0, %1, %2 row_ror:" #S " row_mask:0xf bank_mask:0xf" \
      : "=v"(d) : "v"(x), "v"(a), "v"(dep))

typedef float (*M16)[20];
typedef const float (*CM16)[20];
#define NOM ((CM16)0)

__device__ __forceinline__ float rlf(float v, int lane) {
  return __int_as_float(__builtin_amdgcn_readlane(__float_as_int(v), lane));
}
__device__ __forceinline__ float bpermf(int byteaddr, float v) {
  return __int_as_float(__builtin_amdgcn_ds_bpermute(byteaddr, __float_as_int(v)));
}
template<int CTL> __device__ __forceinline__ float dppf(float x) {
  return __int_as_float(__builtin_amdgcn_update_dpp(
      0, __float_as_int(x), CTL, 0xF, 0xF, false));
}
__device__ __forceinline__ int rot_dir() {
  int r = threadIdx.x & 15;
  int m = __builtin_amdgcn_update_dpp(0, r, 0x121, 0xF, 0xF, false);
  return (m - r) & 15;
}
// y[r] = sum_k A[r][k] x[k], rotated storage a[s] = A[r][(r+s*dir)&15]
__device__ __forceinline__ float mv16(const float a[16], float x) {
  float s0 = a[0] * x;
  float s1, s2, s3;
  MULDPPD(s1, x, a[1], s0, 1);
  MULDPPD(s2, x, a[2], s0, 2);
  MULDPPD(s3, x, a[3], s0, 3);
  FMACDPP(s0, x, a[4], 4);   FMACDPP(s1, x, a[5], 5);
  FMACDPP(s2, x, a[6], 6);   FMACDPP(s3, x, a[7], 7);
  FMACDPP(s0, x, a[8], 8);   FMACDPP(s1, x, a[9], 9);
  FMACDPP(s2, x, a[10], 10); FMACDPP(s3, x, a[11], 11);
  FMACDPP(s0, x, a[12], 12); FMACDPP(s1, x, a[13], 13);
  FMACDPP(s2, x, a[14], 14); FMACDPP(s3, x, a[15], 15);
  return (s0 + s1) + (s2 + s3);
}
// u' = A u + Ktilde z_t; z period-8 replicated -> Ktilde folds to 8 rotations
__device__ __forceinline__ float stepAK(const float a[16], const float k8[8],
                                        float u, float zv) {
  float s0 = __builtin_fmaf(k8[0], zv, a[0] * u);
  float s1, s2, s3;
  MULDPPD(s1, u, a[1], s0, 1);
  MULDPPD(s2, u, a[2], s0, 2);
  MULDPPD(s3, u, a[3], s0, 3);
  FMACDPP(s0, u, a[4], 4);   FMACDPP(s1, u, a[5], 5);
  FMACDPP(s2, u, a[6], 6);   FMACDPP(s3, u, a[7], 7);
  FMACDPP(s0, u, a[8], 8);   FMACDPP(s1, u, a[9], 9);
  FMACDPP(s2, u, a[10], 10); FMACDPP(s3, u, a[11], 11);
  FMACDPP(s0, u, a[12], 12); FMACDPP(s1, u, a[13], 13);
  FMACDPP(s2, u, a[14], 14); FMACDPP(s3, u, a[15], 15);
  FMACDPP(s1, zv, k8[1], 1); FMACDPP(s2, zv, k8[2], 2);
  FMACDPP(s3, zv, k8[3], 3); FMACDPP(s0, zv, k8[4], 4);
  FMACDPP(s1, zv, k8[5], 5); FMACDPP(s2, zv, k8[6], 6);
  FMACDPP(s3, zv, k8[7], 7);
  return (s0 + s1) + (s2 + s3);
}
__device__ __forceinline__ void load16(const float* p, int r, float d[16]) {
  #pragma unroll
  for (int j = 0; j < 4; ++j) {
    float4 t = ((const float4*)p)[r*4 + j];
    d[4*j] = t.x; d[4*j+1] = t.y; d[4*j+2] = t.z; d[4*j+3] = t.w;
  }
}
__device__ __forceinline__ void loadkrf(const float* p, int r, float k8[8]) {
  float kr[16];
  load16(p, r, kr);
  #pragma unroll
  for (int i = 0; i < 8; ++i) k8[i] = kr[i] + kr[i + 8];
}
// replicated z prefetch: zr[t] = z[(s0+t)*8 + (r&7)]; fast path when full
__device__ __forceinline__ void loadz(const float* __restrict__ z, int s0_,
                                      int rr, float zr[L1]) {
  const float* zp = z + (size_t)s0_ * 8 + (rr & 7);
  if (s0_ + L1 <= TT) {
    #pragma unroll
    for (int t = 0; t < L1; ++t) zr[t] = zp[t * 8];
  } else {
    #pragma unroll
    for (int t = 0; t < L1; ++t) {
      const float* q = (s0_ + t < TT) ? (zp + t * 8) : z;
      zr[t] = *q;
    }
  }
}

// ---- 16x16 matrix helpers on [16][20] LDS tiles (64 lanes, 4 outs/lane) ----
__device__ __forceinline__ void mulAB(M16 C, CM16 A, CM16 B, CM16 Add,
                                      bool addI, int r4, int c4) {
  float acc[4];
  #pragma unroll
  for (int j = 0; j < 4; ++j) {
    acc[j] = Add ? Add[r4][c4+j] : 0.f;
    if (addI && r4 == c4 + j) acc[j] += 1.f;
  }
  #pragma unroll
  for (int k = 0; k < 16; ++k) {
    float a = A[r4][k];
    #pragma unroll
    for (int j = 0; j < 4; ++j) acc[j] += a * B[k][c4+j];
  }
  #pragma unroll
  for (int j = 0; j < 4; ++j) C[r4][c4+j] = acc[j];
}
__device__ __forceinline__ void mulATB(M16 C, CM16 A, CM16 B, CM16 Add,
                                       int r4, int c4) {
  float acc[4];
  #pragma unroll
  for (int j = 0; j < 4; ++j) acc[j] = Add ? Add[r4][c4+j] : 0.f;
  #pragma unroll
  for (int k = 0; k < 16; ++k) {
    float a = A[k][r4];
    #pragma unroll
    for (int j = 0; j < 4; ++j) acc[j] += a * B[k][c4+j];
  }
  #pragma unroll
  for (int j = 0; j < 4; ++j) C[r4][c4+j] = acc[j];
}
__device__ __forceinline__ void mulABT(M16 C, CM16 A, CM16 B, CM16 Add,
                                       int r4, int c4) {
  float acc[4];
  #pragma unroll
  for (int j = 0; j < 4; ++j) acc[j] = Add ? Add[r4][c4+j] : 0.f;
  #pragma unroll
  for (int k = 0; k < 16; ++k) {
    float a = A[r4][k];
    #pragma unroll
    for (int j = 0; j < 4; ++j) acc[j] += a * B[c4+j][k];
  }
  #pragma unroll
  for (int j = 0; j < 4; ++j) C[r4][c4+j] = acc[j];
}
// column-lane GJ inverse of well-conditioned D (pivots ~>= 1 by construction)
__device__ __forceinline__ void inv16(CM16 D, M16 V, int l) {
  const int c = l & 31;
  float v[16];
  #pragma unroll
  for (int i = 0; i < 16; ++i)
    v[i] = (c < 16) ? D[i][c] : ((i == c - 16) ? 1.f : 0.f);
  #pragma unroll
  for (int p = 0; p < 16; ++p) {
    float rc = __builtin_amdgcn_rcpf(rlf(v[p], p));
    float fi[16];
    #pragma unroll
    for (int i = 0; i < 16; ++i) fi[i] = rlf(v[i], p) * rc;
    #pragma unroll
    for (int i = 0; i < 16; ++i) if (i != p) v[i] -= fi[i] * v[p];
  }
  #pragma unroll
  for (int i = 0; i < 16; ++i) v[i] *= __builtin_amdgcn_rcpf(rlf(v[i], i));
  if (l >= 16 && l < 32) {
    #pragma unroll
    for (int i = 0; i < 16; ++i) V[i][l - 16] = v[i];
  }
}
// SDA composition: out = f_opnd(f_acc(.)) ; all operands distinct from outs
__device__ void compose(CM16 A1, CM16 G1, CM16 H1,
                        CM16 A2, CM16 G2, CM16 H2,
                        M16 OA, M16 OG, M16 OH,
                        M16 V, M16 D, M16 S1, M16 S2, M16 S3,
                        int l, int r4, int c4) {
  mulAB(D, H1, G2, NOM, true, r4, c4); FENCE_LDS();   // D = I + H1 G2
  inv16(D, V, l); FENCE_LDS();                        // V = U
  mulAB(S1, V, A1, NOM, false, r4, c4); FENCE_LDS();  // S1 = U A1
  mulAB(S2, G2, S1, NOM, false, r4, c4);              // S2 = G2 U A1
  mulAB(S3, V, H1, NOM, false, r4, c4); FENCE_LDS();  // S3 = U H1
  mulAB(OA, A2, S1, NOM, false, r4, c4);              // OA = A2 U A1
  mulATB(OG, A1, S2, G1, r4, c4);                     // OG = G1 + A1^T S2
  mulAB(D, A2, S3, NOM, false, r4, c4); FENCE_LDS();  // D = A2 U H1
  mulABT(OH, D, A2, H2, r4, c4); FENCE_LDS();         // OH = H2 + D A2^T
}
__device__ __forceinline__ void load3(M16 A, M16 G, M16 H,
                                      const float* src, int l) {
  for (int i = l; i < 256; i += 64) {
    A[i>>4][i&15] = src[i];
    G[i>>4][i&15] = src[256 + i];
    H[i>>4][i&15] = src[512 + i];
  }
}

// ---------- kf_prep: base map, 5 doublings, Pb0 ----------
__global__ __launch_bounds__(64) void kf_prep(
    const float* __restrict__ Fg, const float* __restrict__ Qg,
    const float* __restrict__ Rg, float* __restrict__ ws)
{
  const int l = threadIdx.x;
  const int r4 = l >> 2, c4 = (l & 3) * 4;
  __shared__ float MaA[16][20], MaG[16][20], MaH[16][20];
  __shared__ float MoA[16][20], MoG[16][20], MoH[16][20];
  __shared__ float V[16][20], D[16][20], S1[16][20], S2[16][20], S3[16][20];

  for (int i = l; i < 256; i += 64) {
    MaA[i>>4][i&15] = Fg[i];
    MaH[i>>4][i&15] = Qg[i];
    MaG[i>>4][i&15] = 0.f;
  }
  FENCE_LDS();
  // R^-1 -> MaG top-left 8x8 (G = H^T R^-1 H)
  {
    const int c = l & 15;
    float v[8];
    #pragma unroll
    for (int i = 0; i < 8; ++i)
      v[i] = (c < 8) ? Rg[i*8 + c] : ((i == c - 8) ? 1.f : 0.f);
    #pragma unroll
    for (int p = 0; p < 8; ++p) {
      float rc = __builtin_amdgcn_rcpf(rlf(v[p], p));
      float fi[8];
      #pragma unroll
      for (int i = 0; i < 8; ++i) fi[i] = rlf(v[i], p) * rc;
      #pragma unroll
      for (int i = 0; i < 8; ++i) if (i != p) v[i] -= fi[i] * v[p];
    }
    #pragma unroll
    for (int i = 0; i < 8; ++i) v[i] *= __builtin_amdgcn_rcpf(rlf(v[i], i));
    if (l >= 8 && l < 16) {
      #pragma unroll
      for (int i = 0; i < 8; ++i) MaG[i][l - 8] = v[i];
    }
  }
  FENCE_LDS();
  // Pb0 = Q + F F^T -> ws
  mulABT(S1, (CM16)MaA, (CM16)MaA, (CM16)MaH, r4, c4); FENCE_LDS();
  for (int i = l; i < 256; i += 64) ws[OFF_PB0 + i] = S1[i>>4][i&15];
  // store map slot 0 (1 step)
  for (int i = l; i < 256; i += 64) {
    ws[OFF_MAP + i]       = MaA[i>>4][i&15];
    ws[OFF_MAP + 256 + i] = MaG[i>>4][i&15];
    ws[OFF_MAP + 512 + i] = MaH[i>>4][i&15];
  }
  // doublings -> slots 1..5 (2,4,8,16,32 steps)
  for (int j = 1; j <= 5; ++j) {
    compose((CM16)MaA,(CM16)MaG,(CM16)MaH, (CM16)MaA,(CM16)MaG,(CM16)MaH,
            MoA,MoG,MoH, V,D,S1,S2,S3, l,r4,c4);
    for (int i = l; i < 256; i += 64) {
      MaA[i>>4][i&15] = MoA[i>>4][i&15];
      MaG[i>>4][i&15] = MoG[i>>4][i&15];
      MaH[i>>4][i&15] = MoH[i>>4][i&15];
    }
    FENCE_LDS();
    for (int i = l; i < 256; i += 64) {
      ws[OFF_MAP + j*768 + i]       = MaA[i>>4][i&15];
      ws[OFF_MAP + j*768 + 256 + i] = MaG[i>>4][i&15];
      ws[OFF_MAP + j*768 + 512 + i] = MaH[i>>4][i&15];
    }
  }
}

// ---------- kf_kt: per-t SDA evaluation -> K_t; block T0-1 emits A/KR/AL ----
__global__ __launch_bounds__(64) void kf_kt(
    const float* __restrict__ z, const float* __restrict__ Fg,
    const float* __restrict__ Rg, float* __restrict__ ws)
{
  const int l = threadIdx.x;
  const int m = blockIdx.x;
  if (m >= T0) {
    // z-prefetch into L2/L3 (r18 pattern)
    const float4* zv = (const float4*)z;
    const size_t total4 = (size_t)TT * 2;
    const size_t per = (total4 + (NPF - 1)) / NPF;
    size_t s = (size_t)(m - T0) * per;
    size_t e = s + per; if (e > total4) e = total4;
    for (size_t i = s + l; i < e; i += 64) {
      float4 v = zv[i];
      asm volatile("" :: "v"(v.x), "v"(v.y), "v"(v.z), "v"(v.w));
    }
    return;
  }
  const int r4 = l >> 2, c4 = (l & 3) * 4;
  __shared__ float MaA[16][20], MaG[16][20], MaH[16][20];
  __shared__ float MbA[16][20], MbG[16][20], MbH[16][20];
  __shared__ float MoA[16][20], MoG[16][20], MoH[16][20];
  __shared__ float V[16][20], D[16][20], S1[16][20], S2[16][20], S3[16][20];
  __shared__ float Pb0s[16][20], Pbs[16][20];
  __shared__ float KsL[16][8];

  for (int i = l; i < 256; i += 64) Pb0s[i>>4][i&15] = ws[OFF_PB0 + i];
  FENCE_LDS();

  if (m == 0) {
    for (int i = l; i < 256; i += 64) Pbs[i>>4][i&15] = Pb0s[i>>4][i&15];
    FENCE_LDS();
  } else {
    const int k0 = __builtin_ctz(m);
    load3(MaA, MaG, MaH, &ws[OFF_MAP + k0*768], l);
    FENCE_LDS();
    for (int k = k0 + 1; k <= 5; ++k) {
      if (!((m >> k) & 1)) continue;
      load3(MbA, MbG, MbH, &ws[OFF_MAP + k*768], l);
      FENCE_LDS();
      compose((CM16)MaA,(CM16)MaG,(CM16)MaH, (CM16)MbA,(CM16)MbG,(CM16)MbH,
              MoA,MoG,MoH, V,D,S1,S2,S3, l,r4,c4);
      for (int i = l; i < 256; i += 64) {
        MaA[i>>4][i&15] = MoA[i>>4][i&15];
        MaG[i>>4][i&15] = MoG[i>>4][i&15];
        MaH[i>>4][i&15] = MoH[i>>4][i&15];
      }
      FENCE_LDS();
    }
    // evaluate: Pb_m = H + A Pb0 (I + G Pb0)^-1 A^T
    mulAB(D, (CM16)MaG, (CM16)Pb0s, NOM, true, r4, c4); FENCE_LDS();
    inv16((CM16)D, V, l); FENCE_LDS();
    mulAB(S1, (CM16)Pb0s, (CM16)V, NOM, false, r4, c4); FENCE_LDS();
    mulAB(S2, (CM16)MaA, (CM16)S1, NOM, false, r4, c4); FENCE_LDS();
    mulABT(Pbs, (CM16)S2, (CM16)MaA, (CM16)MaH, r4, c4); FENCE_LDS();
  }

  // K_t: solve S K^T = Pb[:8,:] (proven 8-GJ) -> ws KH
  const int  cidx = (l < 8) ? l : ((l < 24) ? (l - 8) : (l & 7));
  const bool isS  = (l < 8);
  const bool isB  = (l >= 8 && l < 24);
  const int  bj   = l - 8;
  float rcol[8];
  {
    int cc = l & 7;
    #pragma unroll
    for (int i = 0; i < 8; ++i) rcol[i] = Rg[i*8 + cc];
  }
  float v8[8];
  #pragma unroll
  for (int i = 0; i < 8; ++i)
    v8[i] = Pbs[i][cidx] + (isS ? rcol[i] : 0.f);
  #pragma unroll
  for (int p = 0; p < 8; ++p) {
    float rc = __builtin_amdgcn_rcpf(rlf(v8[p], p));
    float fi[8];
    #pragma unroll
    for (int i = 0; i < 8; ++i) fi[i] = rlf(v8[i], p) * rc;
    #pragma unroll
    for (int i = 0; i < 8; ++i) if (i != p) v8[i] -= fi[i] * v8[p];
  }
  #pragma unroll
  for (int i = 0; i < 8; ++i) v8[i] *= __builtin_amdgcn_rcpf(rlf(v8[i], i));
  if (isB) {
    #pragma unroll
    for (int i = 0; i < 8; ++i) ws[OFF_KH + m*128 + bj*8 + i] = v8[i];
  }

  if (m != T0 - 1) return;

  // ---- epilogue (block T0-1): A = F - K F[:8,:], Ktilde, A^32 (rotated) ----
  const int dir = rot_dir();
  if (isB) {
    #pragma unroll
    for (int i = 0; i < 8; ++i) KsL[bj][i] = v8[i];
  }
  FENCE_LDS();
  const int ba = (8 + r4) << 2;
  float kk[8];
  #pragma unroll
  for (int i = 0; i < 8; ++i) kk[i] = bpermf(ba, v8[i]);
  float a[4];
  #pragma unroll
  for (int j = 0; j < 4; ++j) {
    float s = Fg[r4*16 + c4 + j];
    #pragma unroll
    for (int k = 0; k < 8; ++k) s -= kk[k] * Fg[k*16 + c4 + j];
    a[j] = s;
  }
  #pragma unroll
  for (int j = 0; j < 4; ++j) S1[r4][c4 + j] = a[j];   // S1 := A (plain)
  #pragma unroll
  for (int j = 0; j < 4; ++j) {
    int c = c4 + j;
    int s = ((c - r4) * dir) & 15;
    ws[OFF_A + r4*16 + s] = a[j];
  }
  FENCE_LDS();
  if (l < 16) {
    #pragma unroll
    for (int s = 0; s < 16; ++s) {
      int c = (l + s*dir) & 15;
      ws[OFF_KR + l*16 + s] = (c < 8) ? KsL[l][c] : 0.f;
    }
  }
  FENCE_LDS();
  // squarings on S1/S2: after n, matrix = A^(2^(n+1)); n==4 -> A^32
  for (int n = 0; n < 5; ++n) {
    float (*src)[20] = (n & 1) ? S2 : S1;
    float (*dst)[20] = (n & 1) ? S1 : S2;
    float b[4] = {0.f, 0.f, 0.f, 0.f};
    #pragma unroll
    for (int k = 0; k < 16; ++k) {
      float mm = src[r4][k];
      const float* p = &src[k][c4];
      b[0] += mm*p[0]; b[1] += mm*p[1]; b[2] += mm*p[2]; b[3] += mm*p[3];
    }
    FENCE_LDS();
    dst[r4][c4]=b[0]; dst[r4][c4+1]=b[1]; dst[r4][c4+2]=b[2]; dst[r4][c4+3]=b[3];
    FENCE_LDS();
    if (n == 4) {
      #pragma unroll
      for (int j = 0; j < 4; ++j) {
        int c = c4 + j;
        int s = ((c - r4) * dir) & 15;
        ws[OFF_AL + r4*16 + s] = b[j];
      }
    }
  }
}

// ---------- Pair scan: r18 verbatim (8 ghost + 32 pair groups) ----------
__global__ __launch_bounds__(NTHR) void kf_scan(
    const float* __restrict__ z, const float* __restrict__ Fg,
    float* __restrict__ ws, float* __restrict__ out)
{
  const int tid = threadIdx.x;
  const int bid = blockIdx.x;
  const int r = tid & 15;
  const int g = tid >> 4;            // 0..39

  __shared__ float ueL[(GH + OWN) * 16];
  __shared__ float X0s[16];

  float a[16], krf[8];
  load16(&ws[OFF_A], r, a);
  loadkrf(&ws[OFF_KR], r, krf);

  float zrA[L1], zrB[L1];
  int cA = -1, cB = -1, lenB = 0, s0A = 0, s0B = 0;

  if (g < GH) {
    if (bid == 0) {
      if (g == 0) {
        // exact t<T0 head recursion with time-varying K_t (lanes 0..15)
        float f[16];
        #pragma unroll
        for (int i = 0; i < 16; ++i) f[i] = Fg[r*16 + i];
        const float4* zb = (const float4*)z + r;
        const float4* kh = (const float4*)&ws[OFF_KH] + r*2;
        float x = 0.f;
        float4 d0 = zb[0], d1 = zb[16];
        float4 ka0 = kh[0],  kb0 = kh[1];
        float4 ka1 = kh[32], kb1 = kh[33];
        for (int b = 0; b < T0/8; ++b) {
          float4 nx = (b + 2 < T0/8) ? zb[(b+2)*16] : make_float4(0.f,0.f,0.f,0.f);
          #pragma unroll
          for (int j = 0; j < 8; ++j) {
            const int t = b*8 + j;
            float p0=0.f,p1=0.f,p2=0.f,p3=0.f;
            #pragma unroll
            for (int k = 0; k < 16; k += 4) {
              p0 += f[k]   * __shfl(x, k, 16);
              p1 += f[k+1] * __shfl(x, k+1, 16);
              p2 += f[k+2] * __shfl(x, k+2, 16);
              p3 += f[k+3] * __shfl(x, k+3, 16);
            }
            float xp = (p0+p1)+(p2+p3);
            float z0=__shfl(d0.x,2*j,16),   z1=__shfl(d0.y,2*j,16);
            float z2=__shfl(d0.z,2*j,16),   z3=__shfl(d0.w,2*j,16);
            float z4=__shfl(d0.x,2*j+1,16), z5=__shfl(d0.y,2*j+1,16);
            float z6=__shfl(d0.z,2*j+1,16), z7=__shfl(d0.w,2*j+1,16);
            float acc = xp;
            acc += ka0.x * (z0 - __shfl(xp,0,16));
            acc += ka0.y * (z1 - __shfl(xp,1,16));
            acc += ka0.z * (z2 - __shfl(xp,2,16));
            acc += ka0.w * (z3 - __shfl(xp,3,16));
            acc += kb0.x * (z4 - __shfl(xp,4,16));
            acc += kb0.y * (z5 - __shfl(xp,5,16));
            acc += kb0.z * (z6 - __shfl(xp,6,16));
            acc += kb0.w * (z7 - __shfl(xp,7,16));
            x = acc;
            out[t*16 + r] = x;
            ka0 = ka1; kb0 = kb1;
            if (t + 2 < T0) { ka1 = kh[(t+2)*32]; kb1 = kh[(t+2)*32 + 1]; }
          }
          d0 = d1; d1 = nx;
        }
        X0s[r] = x;
      }
    } else {
      int cg = bid*OWN - GH + g;       // ghost chunk (always full-length)
      int s0_ = T0 + cg*L1;
      loadz(z, s0_, r, zrA);
      float u = 0.f;
      #pragma unroll
      for (int t = 0; t < L1; ++t) u = stepAK(a, krf, u, zrA[t]);
      ueL[g*16 + r] = u;
    }
  } else {
    int k = g - GH;                    // pair index 0..31
    cA = bid*OWN + 2*k;
    if (cA < NCHUNK) {
      s0A = T0 + cA*L1;
      loadz(z, s0A, r, zrA);
      float u = 0.f;
      #pragma unroll
      for (int t = 0; t < L1; ++t) {
        u = stepAK(a, krf, u, zrA[t]);
        zrA[t] = u;
      }
      ueL[(GH + 2*k)*16 + r] = u;
      cB = cA + 1;
      if (cB < NCHUNK) {
        s0B = s0A + L1;
        lenB = min(s0B + L1, TT) - s0B;
        loadz(z, s0B, r, zrB);
        u = 0.f;
        #pragma unroll
        for (int t = 0; t < L1; ++t) {
          if (t >= lenB) break;
          u = stepAK(a, krf, u, zrB[t]);
          zrB[t] = u;
        }
        ueL[(GH + 2*k + 1)*16 + r] = u;
      }
    } else {
      cA = -1;
    }
  }
  float al[16];
  load16(&ws[OFF_AL], r, al);
  __syncthreads();

  if (cA >= 0) {
    const int kp2 = 2*(g - GH);
    float v = 0.f;
    if (cA >= GH) {
      float w8[GH];
      #pragma unroll
      for (int mm = 0; mm < GH; ++mm) w8[mm] = ueL[(kp2 + mm)*16 + r];
      #pragma unroll
      for (int mm = 0; mm < GH; ++mm) v = mv16(al, v) + w8[mm];
    } else {
      v = X0s[r];
      for (int j = 0; j < cA; ++j)
        v = mv16(al, v) + ueL[(GH + j)*16 + r];
    }
    float w = v;
    #pragma unroll
    for (int t = 0; t < L1; ++t) {
      w = mv16(a, w);
      out[(size_t)(s0A + t)*16 + r] = zrA[t] + w;
    }
    if (cB < NCHUNK && cB >= 0) {
      w = zrA[L1-1] + w;
      #pragma unroll
      for (int t = 0; t < L1; ++t) {
        if (t >= lenB) break;
        w = mv16(a, w);
        out[(size_t)(s0B + t)*16 + r] = zrB[t] + w;
      }
    }
  }
}

extern "C" void kernel_launch(void* const* d_in, const int* in_sizes, int n_in,
                              void* d_out, int out_size, void* d_ws, size_t ws_size,
                              hipStream_t stream) {
  const float* z  = (const float*)d_in[0];
  const float* Fg = (const float*)d_in[1];
  const float* Qg = (const float*)d_in[3];
  const float* Rg = (const float*)d_in[4];
  float* out = (float*)d_out;
  float* ws  = (float*)d_ws;

  kf_prep<<<1, 64, 0, stream>>>(Fg, Qg, Rg, ws);
  kf_kt<<<T0 + NPF, 64, 0, stream>>>(z, Fg, Rg, ws);
  kf_scan<<<NBLK2, NTHR, 0, stream>>>(z, Fg, ws, out);
}

// Round 21
// 74.494 us; speedup vs baseline: 1.6060x; 1.6060x over previous
//
#include <hip/hip_runtime.h>

// Kalman filter, STATE=16, MEAS=8, T=500000. H==eye(8,16), exploited throughout.
//
// Round-21: r18 compute path VERBATIM (76.1us known-good) + DVFS-boost test.
// Hypothesis: every single-wave serial kernel in this session ran ~5x slower
// than its dependency-chain theory (ricc 2900cy/step vs ~700; SDA compose
// ~10us vs ~2) because 1 wave on 1 CU leaves SCLK at idle (~600MHz) -- the
// governor never ramps. Blocks 1..244 of kf_ricc now run a pure-VALU FMA
// busy loop, dual-capped (4000 realtime ticks ~= 40us @100MHz const clock,
// AND 250 iters ~= 35us at IDLE clock) so worst case adds ~2us; if the
// theory holds, ricc's own dispatch time collapses.
//
// kf_ricc (245 x 64): block 0: 40 exact Riccati steps (FENCE_LDS single-wave
//   fences, reg-resident stage B, readlane GJ; emits A/Ktilde/A^32 rotated +
//   K_t history to ws). blocks 1+: DVFS booster, then exit.
// kf_scan (245 x 640): 40 groups = 8 ghost + 32 pair groups (64 owned chunks,
//   L=32). Pass 1: scans from 0 -> u_end in LDS, u-history in regs. Block 0
//   group 0 runs the exact t<T0 head. Pass 2: compose xinA from 8 LDS u_end
//   entries (A^32; span 256 steps, ||A^256||~3e-10 of the window tail),
//   out_t = u_t + A^(t+1) xin, chain into chunk B.

#define TT 500000
#define T0 40
#define L1 32
#define NCHUNK 15624           // ceil((TT-T0)/L1); last chunk = 24 steps
#define GH 8                   // ghost chunks = window entries
#define OWN 64                 // owned chunks per block (32 pairs)
#define NBLK2 245              // ceil(NCHUNK/OWN)
#define NTHR (16 * (GH + OWN/2))   // 640

#define OFF_A    0             // 16x16 rotated  A=(I-KH)F
#define OFF_KR   256           // 16x16 rotated  Ktilde
#define OFF_AL   512           // 16x16 rotated  A^32
#define OFF_KH   784           // T0*128 plain K_t history

// single-wave LDS fence: order ds_write -> ds_read without draining vmcnt
#define FENCE_LDS() do { \
  asm volatile("s_waitcnt lgkmcnt(0)" ::: "memory"); \
  __builtin_amdgcn_sched_barrier(0); \
} while (0)

// DPP-fused FMA: d += rot_S(x) * a; dep keeps the DPP source >=2 VALU old.
#define FMACDPP(d, x, a, S) \
  asm("v_fmac_f32_dpp %0, %1, %2 row_ror:" #S " row_mask:0xf bank_mask:0xf" \
      : "+v"(d) : "v"(x), "v"(a))
#define MULDPPD(d, x, a, dep, S) \
  asm("v_mul_f32_dpp %0, %1, %2 row_ror:" #S " row_mask:0xf bank_mask:0xf" \
      : "=v"(d) : "v"(x), "v"(a), "v"(dep))

__device__ __forceinline__ float rlf(float v, int lane) {
  return __int_as_float(__builtin_amdgcn_readlane(__float_as_int(v), lane));
}
__device__ __forceinline__ float bpermf(int byteaddr, float v) {
  return __int_as_float(__builtin_amdgcn_ds_bpermute(byteaddr, __float_as_int(v)));
}
template<int CTL> __device__ __forceinline__ float dppf(float x) {
  return __int_as_float(__builtin_amdgcn_update_dpp(
      0, __float_as_int(x), CTL, 0xF, 0xF, false));
}
#define QP1 0x39
#define QP2 0x4E
#define QP3 0x93

__device__ __forceinline__ unsigned long long rtclock() {
  unsigned long long t;
  asm volatile("s_memrealtime %0\n\ts_waitcnt lgkmcnt(0)" : "=s"(t));
  return t;
}

__device__ __forceinline__ int rot_dir() {
  int r = threadIdx.x & 15;
  int m = __builtin_amdgcn_update_dpp(0, r, 0x121, 0xF, 0xF, false);
  return (m - r) & 15;
}
// y[r] = sum_k A[r][k] x[k], rotated storage a[s] = A[r][(r+s*dir)&15]
__device__ __forceinline__ float mv16(const float a[16], float x) {
  float s0 = a[0] * x;
  float s1, s2, s3;
  MULDPPD(s1, x, a[1], s0, 1);
  MULDPPD(s2, x, a[2], s0, 2);
  MULDPPD(s3, x, a[3], s0, 3);
  FMACDPP(s0, x, a[4], 4);   FMACDPP(s1, x, a[5], 5);
  FMACDPP(s2, x, a[6], 6);   FMACDPP(s3, x, a[7], 7);
  FMACDPP(s0, x, a[8], 8);   FMACDPP(s1, x, a[9], 9);
  FMACDPP(s2, x, a[10], 10); FMACDPP(s3, x, a[11], 11);
  FMACDPP(s0, x, a[12], 12); FMACDPP(s1, x, a[13], 13);
  FMACDPP(s2, x, a[14], 14); FMACDPP(s3, x, a[15], 15);
  return (s0 + s1) + (s2 + s3);
}
// u' = A u + Ktilde z_t; z period-8 replicated -> Ktilde folds to 8 rotations
__device__ __forceinline__ float stepAK(const float a[16], const float k8[8],
                                        float u, float zv) {
  float s0 = __builtin_fmaf(k8[0], zv, a[0] * u);
  float s1, s2, s3;
  MULDPPD(s1, u, a[1], s0, 1);
  MULDPPD(s2, u, a[2], s0, 2);
  MULDPPD(s3, u, a[3], s0, 3);
  FMACDPP(s0, u, a[4], 4);   FMACDPP(s1, u, a[5], 5);
  FMACDPP(s2, u, a[6], 6);   FMACDPP(s3, u, a[7], 7);
  FMACDPP(s0, u, a[8], 8);   FMACDPP(s1, u, a[9], 9);
  FMACDPP(s2, u, a[10], 10); FMACDPP(s3, u, a[11], 11);
  FMACDPP(s0, u, a[12], 12); FMACDPP(s1, u, a[13], 13);
  FMACDPP(s2, u, a[14], 14); FMACDPP(s3, u, a[15], 15);
  FMACDPP(s1, zv, k8[1], 1); FMACDPP(s2, zv, k8[2], 2);
  FMACDPP(s3, zv, k8[3], 3); FMACDPP(s0, zv, k8[4], 4);
  FMACDPP(s1, zv, k8[5], 5); FMACDPP(s2, zv, k8[6], 6);
  FMACDPP(s3, zv, k8[7], 7);
  return (s0 + s1) + (s2 + s3);
}
__device__ __forceinline__ void load16(const float* p, int r, float d[16]) {
  #pragma unroll
  for (int j = 0; j < 4; ++j) {
    float4 t = ((const float4*)p)[r*4 + j];
    d[4*j] = t.x; d[4*j+1] = t.y; d[4*j+2] = t.z; d[4*j+3] = t.w;
  }
}
__device__ __forceinline__ void loadkrf(const float* p, int r, float k8[8]) {
  float kr[16];
  load16(p, r, kr);
  #pragma unroll
  for (int i = 0; i < 8; ++i) k8[i] = kr[i] + kr[i + 8];
}
// replicated z prefetch: zr[t] = z[(s0+t)*8 + (r&7)]; fast path when full
__device__ __forceinline__ void loadz(const float* __restrict__ z, int s0_,
                                      int rr, float zr[L1]) {
  const float* zp = z + (size_t)s0_ * 8 + (rr & 7);
  if (s0_ + L1 <= TT) {
    #pragma unroll
    for (int t = 0; t < L1; ++t) zr[t] = zp[t * 8];
  } else {
    #pragma unroll
    for (int t = 0; t < L1; ++t) {
      const float* q = (s0_ + t < TT) ? (zp + t * 8) : z;
      zr[t] = *q;
    }
  }
}

// block 0: serial Riccati; blocks 1+: DVFS booster (pure VALU, dual-capped)
__global__ __launch_bounds__(64) void kf_ricc(
    const float* __restrict__ Fg, const float* __restrict__ Qg,
    const float* __restrict__ Rg, float* __restrict__ ws)
{
  const int bid = blockIdx.x;
  if (bid != 0) {
    unsigned long long t0c = rtclock();
    float x = 1.0f + (float)threadIdx.x * 1e-7f;
    #pragma unroll 1
    for (int it = 0; it < 250; ++it) {
      #pragma unroll
      for (int j = 0; j < 48; ++j)
        x = __builtin_fmaf(x, 1.0000001f, 1e-30f);
      if (rtclock() - t0c > 4000ull) break;   // ~40us at 100MHz const clock
    }
    asm volatile("" :: "v"(x));
    return;
  }

  const int l  = threadIdx.x;
  const int r4 = l >> 2;
  const int q  = l & 3;
  const int c4 = q * 4;
  const int dir = rot_dir();

  __shared__ float Ps[16][20], Pbs[16][20], Ms[16][20];
  __shared__ float KsL[16][8];

  float frow[16];
  #pragma unroll
  for (int k = 0; k < 16; ++k) frow[k] = Fg[r4*16 + k];
  float4 ftr[16];
  #pragma unroll
  for (int d = 0; d < 4; ++d) {
    #pragma unroll
    for (int jp = 0; jp < 4; ++jp) {
      int col = 4*((q + d) & 3) + jp;
      ftr[d*4+jp] = make_float4(Fg[(c4+0)*16 + col], Fg[(c4+1)*16 + col],
                                Fg[(c4+2)*16 + col], Fg[(c4+3)*16 + col]);
    }
  }
  float4 qreg = *(const float4*)&Qg[r4*16 + c4];
  float rcol[8];
  {
    int cc = l & 7;
    #pragma unroll
    for (int i = 0; i < 8; ++i) rcol[i] = Rg[i*8 + cc];
  }
  *(float4*)&Ps[r4][c4] = make_float4(r4==c4 ?1.f:0.f, r4==c4+1?1.f:0.f,
                                      r4==c4+2?1.f:0.f, r4==c4+3?1.f:0.f);
  const int  cidx = (l < 8) ? l : ((l < 24) ? (l - 8) : (l & 7));
  const bool isS  = (l < 8);
  const bool isB  = (l >= 8 && l < 24);
  const int  bj   = l - 8;
  const int  ba   = (8 + r4) << 2;    // bpermute src: lane 8+r4 holds K row r4
  float v[8];
  FENCE_LDS();

  for (int t = 0; t < T0; ++t) {
    // stage A: M[r4][c4..3] = F[r4][:] * P[:, c4..3]
    float m0=0.f,m1=0.f,m2=0.f,m3=0.f;
    #pragma unroll
    for (int k = 0; k < 16; ++k) {
      float4 pk = *(const float4*)&Ps[k][c4];
      float f = frow[k];
      m0 += f*pk.x; m1 += f*pk.y; m2 += f*pk.z; m3 += f*pk.w;
    }
    float g1x=dppf<QP1>(m0), g1y=dppf<QP1>(m1), g1z=dppf<QP1>(m2), g1w=dppf<QP1>(m3);
    float g2x=dppf<QP2>(m0), g2y=dppf<QP2>(m1), g2z=dppf<QP2>(m2), g2w=dppf<QP2>(m3);
    float g3x=dppf<QP3>(m0), g3y=dppf<QP3>(m1), g3z=dppf<QP3>(m2), g3w=dppf<QP3>(m3);
    const float mq[4][4] = {{m0,m1,m2,m3},{g1x,g1y,g1z,g1w},
                            {g2x,g2y,g2z,g2w},{g3x,g3y,g3z,g3w}};
    // stage B: Pb = M * F^T + Q, in registers
    float b0=qreg.x, b1=qreg.y, b2=qreg.z, b3=qreg.w;
    #pragma unroll
    for (int d = 0; d < 4; ++d) {
      #pragma unroll
      for (int jp = 0; jp < 4; ++jp) {
        float mm = mq[d][jp];
        float4 ft = ftr[d*4+jp];
        b0 += mm*ft.x; b1 += mm*ft.y; b2 += mm*ft.z; b3 += mm*ft.w;
      }
    }
    float4 pb = make_float4(b0,b1,b2,b3);
    *(float4*)&Pbs[r4][c4] = pb;
    FENCE_LDS();
    // readlane Gauss-Jordan on [S | B]: solve S X = B, X = K^T
    #pragma unroll
    for (int i = 0; i < 8; ++i)
      v[i] = Pbs[i][cidx] + (isS ? rcol[i] : 0.f);
    #pragma unroll
    for (int p = 0; p < 8; ++p) {
      float piv = rlf(v[p], p);
      float rc  = __builtin_amdgcn_rcpf(piv);
      float fi[8];
      #pragma unroll
      for (int i = 0; i < 8; ++i) fi[i] = rlf(v[i], p) * rc;
      #pragma unroll
      for (int i = 0; i < 8; ++i) if (i != p) v[i] -= fi[i] * v[p];
    }
    {
      float dv[8];
      #pragma unroll
      for (int i = 0; i < 8; ++i) dv[i] = __builtin_amdgcn_rcpf(rlf(v[i], i));
      #pragma unroll
      for (int i = 0; i < 8; ++i) v[i] *= dv[i];
    }
    if (isB) {                       // lane 8+j holds K row j
      #pragma unroll
      for (int i = 0; i < 8; ++i) ws[OFF_KH + t*128 + bj*8 + i] = v[i];
    }
    float kk[8];
    #pragma unroll
    for (int i = 0; i < 8; ++i) kk[i] = bpermf(ba, v[i]);
    // P = Pb - K * Pb[:8,:]
    float4 pn = pb;
    #pragma unroll
    for (int k = 0; k < 8; ++k) {
      float4 pr = *(const float4*)&Pbs[k][c4];
      float kv = kk[k];
      pn.x -= kv*pr.x; pn.y -= kv*pr.y; pn.z -= kv*pr.z; pn.w -= kv*pr.w;
    }
    *(float4*)&Ps[r4][c4] = pn;
    FENCE_LDS();
  }

  // epilogue: K rows to LDS; A = F - K*F[:8,:]
  if (isB) {
    #pragma unroll
    for (int i = 0; i < 8; ++i) KsL[bj][i] = v[i];
  }
  float kk[8];
  #pragma unroll
  for (int i = 0; i < 8; ++i) kk[i] = bpermf(ba, v[i]);
  float a[4];
  #pragma unroll
  for (int j = 0; j < 4; ++j) {
    float s = Fg[r4*16 + c4 + j];
    #pragma unroll
    for (int k = 0; k < 8; ++k) s -= kk[k] * Fg[k*16 + c4 + j];
    a[j] = s;
  }
  *(float4*)&Ms[r4][c4] = make_float4(a[0],a[1],a[2],a[3]);
  #pragma unroll
  for (int j = 0; j < 4; ++j) {
    int c = c4 + j;
    int s = ((c - r4) * dir) & 15;
    ws[OFF_A + r4*16 + s] = a[j];
  }
  FENCE_LDS();
  if (l < 16) {
    #pragma unroll
    for (int s = 0; s < 16; ++s) {
      int c = (l + s*dir) & 15;
      ws[OFF_KR + l*16 + s] = (c < 8) ? KsL[l][c] : 0.f;
    }
  }
  FENCE_LDS();
  // squarings: after n, matrix = A^(2^(n+1)); n==4 -> A^32
  for (int n = 0; n < 5; ++n) {
    float (*src)[20] = (n & 1) ? Pbs : Ms;
    float (*dst)[20] = (n & 1) ? Ms : Pbs;
    float b[4] = {0.f, 0.f, 0.f, 0.f};
    #pragma unroll
    for (int k = 0; k < 16; ++k) {
      float m = src[r4][k];
      const float* p = &src[k][c4];
      b[0] += m*p[0]; b[1] += m*p[1]; b[2] += m*p[2]; b[3] += m*p[3];
    }
    FENCE_LDS();
    dst[r4][c4]=b[0]; dst[r4][c4+1]=b[1]; dst[r4][c4+2]=b[2]; dst[r4][c4+3]=b[3];
    FENCE_LDS();
    if (n == 4) {
      #pragma unroll
      for (int j = 0; j < 4; ++j) {
        int c = c4 + j;
        int s = ((c - r4) * dir) & 15;
        ws[OFF_AL + r4*16 + s] = b[j];
      }
    }
  }
}

// Pair scan: 40 groups = 8 ghost + 32 pair groups (64 owned chunks).
__global__ __launch_bounds__(NTHR) void kf_scan(
    const float* __restrict__ z, const float* __restrict__ Fg,
    float* __restrict__ ws, float* __restrict__ out)
{
  const int tid = threadIdx.x;
  const int bid = blockIdx.x;
  const int r = tid & 15;
  const int g = tid >> 4;            // 0..39

  __shared__ float ueL[(GH + OWN) * 16];
  __shared__ float X0s[16];

  float a[16], krf[8];
  load16(&ws[OFF_A], r, a);
  loadkrf(&ws[OFF_KR], r, krf);

  float zrA[L1], zrB[L1];
  int cA = -1, cB = -1, lenB = 0, s0A = 0, s0B = 0;

  // ---- pass 1: local scans from 0 (+ head in block 0 group 0) ----
  if (g < GH) {
    if (bid == 0) {
      if (g == 0) {
        // exact t<T0 head recursion with time-varying K_t (lanes 0..15)
        float f[16];
        #pragma unroll
        for (int i = 0; i < 16; ++i) f[i] = Fg[r*16 + i];
        const float4* zb = (const float4*)z + r;
        const float4* kh = (const float4*)&ws[OFF_KH] + r*2;
        float x = 0.f;
        float4 d0 = zb[0], d1 = zb[16];
        float4 ka0 = kh[0],  kb0 = kh[1];
        float4 ka1 = kh[32], kb1 = kh[33];
        for (int b = 0; b < T0/8; ++b) {
          float4 nx = (b + 2 < T0/8) ? zb[(b+2)*16] : make_float4(0.f,0.f,0.f,0.f);
          #pragma unroll
          for (int j = 0; j < 8; ++j) {
            const int t = b*8 + j;
            float p0=0.f,p1=0.f,p2=0.f,p3=0.f;
            #pragma unroll
            for (int k = 0; k < 16; k += 4) {
              p0 += f[k]   * __shfl(x, k, 16);
              p1 += f[k+1] * __shfl(x, k+1, 16);
              p2 += f[k+2] * __shfl(x, k+2, 16);
              p3 += f[k+3] * __shfl(x, k+3, 16);
            }
            float xp = (p0+p1)+(p2+p3);
            float z0=__shfl(d0.x,2*j,16),   z1=__shfl(d0.y,2*j,16);
            float z2=__shfl(d0.z,2*j,16),   z3=__shfl(d0.w,2*j,16);
            float z4=__shfl(d0.x,2*j+1,16), z5=__shfl(d0.y,2*j+1,16);
            float z6=__shfl(d0.z,2*j+1,16), z7=__shfl(d0.w,2*j+1,16);
            float acc = xp;
            acc += ka0.x * (z0 - __shfl(xp,0,16));
            acc += ka0.y * (z1 - __shfl(xp,1,16));
            acc += ka0.z * (z2 - __shfl(xp,2,16));
            acc += ka0.w * (z3 - __shfl(xp,3,16));
            acc += kb0.x * (z4 - __shfl(xp,4,16));
            acc += kb0.y * (z5 - __shfl(xp,5,16));
            acc += kb0.z * (z6 - __shfl(xp,6,16));
            acc += kb0.w * (z7 - __shfl(xp,7,16));
            x = acc;
            out[t*16 + r] = x;
            ka0 = ka1; kb0 = kb1;
            if (t + 2 < T0) { ka1 = kh[(t+2)*32]; kb1 = kh[(t+2)*32 + 1]; }
          }
          d0 = d1; d1 = nx;
        }
        X0s[r] = x;
      }
      // block 0 has no ghosts; groups 1..GH-1 idle in pass 1
    } else {
      int cg = bid*OWN - GH + g;       // ghost chunk (always full-length)
      int s0_ = T0 + cg*L1;
      loadz(z, s0_, r, zrA);
      float u = 0.f;
      #pragma unroll
      for (int t = 0; t < L1; ++t) u = stepAK(a, krf, u, zrA[t]);
      ueL[g*16 + r] = u;
    }
  } else {
    int k = g - GH;                    // pair index 0..31
    cA = bid*OWN + 2*k;
    if (cA < NCHUNK) {
      s0A = T0 + cA*L1;
      loadz(z, s0A, r, zrA);
      float u = 0.f;
      #pragma unroll
      for (int t = 0; t < L1; ++t) {
        u = stepAK(a, krf, u, zrA[t]);
        zrA[t] = u;
      }
      ueL[(GH + 2*k)*16 + r] = u;
      cB = cA + 1;
      if (cB < NCHUNK) {
        s0B = s0A + L1;
        lenB = min(s0B + L1, TT) - s0B;
        loadz(z, s0B, r, zrB);
        u = 0.f;
        #pragma unroll
        for (int t = 0; t < L1; ++t) {
          if (t >= lenB) break;
          u = stepAK(a, krf, u, zrB[t]);
          zrB[t] = u;
        }
        ueL[(GH + 2*k + 1)*16 + r] = u;
      }
    } else {
      cA = -1;
    }
  }
  float al[16];
  load16(&ws[OFF_AL], r, al);
  __syncthreads();

  // ---- pass 2: compose xinA; out = u + w; chain into chunk B ----
  if (cA >= 0) {
    const int kp2 = 2*(g - GH);
    float v = 0.f;
    if (cA >= GH) {
      float w8[GH];
      #pragma unroll
      for (int mm = 0; mm < GH; ++mm) w8[mm] = ueL[(kp2 + mm)*16 + r];
      #pragma unroll
      for (int mm = 0; mm < GH; ++mm) v = mv16(al, v) + w8[mm];
    } else {
      // block 0 short window from x_{T0-1} (exact)
      v = X0s[r];
      for (int j = 0; j < cA; ++j)
        v = mv16(al, v) + ueL[(GH + j)*16 + r];
    }
    float w = v;
    #pragma unroll
    for (int t = 0; t < L1; ++t) {
      w = mv16(a, w);
      out[(size_t)(s0A + t)*16 + r] = zrA[t] + w;
    }
    if (cB < NCHUNK && cB >= 0) {
      w = zrA[L1-1] + w;               // xinB = uendA + A^32 xinA
      #pragma unroll
      for (int t = 0; t < L1; ++t) {
        if (t >= lenB) break;
        w = mv16(a, w);
        out[(size_t)(s0B + t)*16 + r] = zrB[t] + w;
      }
    }
  }
}

extern "C" void kernel_launch(void* const* d_in, const int* in_sizes, int n_in,
                              void* d_out, int out_size, void* d_ws, size_t ws_size,
                              hipStream_t stream) {
  const float* z  = (const float*)d_in[0];
  const float* Fg = (const float*)d_in[1];
  const float* Qg = (const float*)d_in[3];
  const float* Rg = (const float*)d_in[4];
  float* out = (float*)d_out;
  float* ws  = (float*)d_ws;

  kf_ricc<<<NBLK2, 64, 0, stream>>>(Fg, Qg, Rg, ws);
  kf_scan<<<NBLK2, NTHR, 0, stream>>>(z, Fg, ws, out);
}